// Round 4
// baseline (1417.250 us; speedup 1.0000x reference)
//
#include <hip/hip_runtime.h>

typedef __bf16 bf16x8 __attribute__((ext_vector_type(8)));
typedef __bf16 bf16x4 __attribute__((ext_vector_type(4)));
typedef float f32x4 __attribute__((ext_vector_type(4)));

#define B_ 2
#define S_ 2048
#define D_ 4096
#define H_ 32
#define KV_ 8
#define G_ 4
#define HD_ 128
#define P_ 1024
#define T_ 3072

__device__ inline bf16x8 cvt8(const float4 a, const float4 b) {
  bf16x8 r;
  r[0] = (__bf16)a.x; r[1] = (__bf16)a.y; r[2] = (__bf16)a.z; r[3] = (__bf16)a.w;
  r[4] = (__bf16)b.x; r[5] = (__bf16)b.y; r[6] = (__bf16)b.z; r[7] = (__bf16)b.w;
  return r;
}

// ---------------- f32 -> bf16 elementwise convert (8 elems/thread) ----------
__global__ __launch_bounds__(256) void cvt_f32_bf16(const float* __restrict__ in,
                                                    __bf16* __restrict__ out) {
  const long i = ((long)blockIdx.x * 256 + threadIdx.x) * 8;
  float4 a = *(const float4*)(in + i);
  float4 b = *(const float4*)(in + i + 4);
  *(bf16x8*)(out + i) = cvt8(a, b);
}

// ------------- transpose: out[c][r] = bf16(in[r][c]), in f32 R x C ----------
__global__ __launch_bounds__(256) void transpose2d(const float* __restrict__ in,
                                                   __bf16* __restrict__ out,
                                                   int R, int C) {
  __shared__ float tl[32][33];
  const int tx = threadIdx.x, ty = threadIdx.y;
  const int c0 = blockIdx.x * 32, r0 = blockIdx.y * 32;
#pragma unroll
  for (int i = 0; i < 4; ++i)
    tl[ty + i * 8][tx] = in[(long)(r0 + ty + i * 8) * C + c0 + tx];
  __syncthreads();
#pragma unroll
  for (int i = 0; i < 4; ++i)
    out[(long)(c0 + ty + i * 8) * R + r0 + tx] = (__bf16)tl[tx][ty + i * 8];
}

// ------- build transposed+concatenated V: vt[b][kvh][hd][j], j in [0,T) -----
__global__ __launch_bounds__(256) void build_vt(const float* __restrict__ past_v,
                                                const __bf16* __restrict__ vn,
                                                __bf16* __restrict__ vt) {
  __shared__ float tl[32][33];
  const int tx = threadIdx.x, ty = threadIdx.y;
  const int j0 = blockIdx.x * 32, hd0 = blockIdx.y * 32;
  const int b = blockIdx.z >> 3, kvh = blockIdx.z & 7;
#pragma unroll
  for (int i = 0; i < 4; ++i) {
    const int j = j0 + ty + i * 8;
    float val = (j < P_)
        ? past_v[((long)((b * P_ + j) * KV_ + kvh)) * HD_ + hd0 + tx]
        : (float)vn[((long)((b * S_ + (j - P_)) * KV_ + kvh)) * HD_ + hd0 + tx];
    tl[ty + i * 8][tx] = val;
  }
  __syncthreads();
#pragma unroll
  for (int i = 0; i < 4; ++i)
    vt[((long)((b * KV_ + kvh) * HD_ + hd0 + ty + i * 8)) * T_ + j0 + tx] =
        (__bf16)tl[tx][ty + i * 8];
}

// ------- build concatenated bf16 K: kc[b][kvh][j][hd], j in [0,T) -----------
__global__ __launch_bounds__(256) void build_kc(const float* __restrict__ pk,
                                                const __bf16* __restrict__ kn,
                                                __bf16* __restrict__ kc) {
  const int idx = blockIdx.x * 256 + threadIdx.x;
  const int row = idx >> 4, ch = (idx & 15) * 8;  // row in [0, B*KV*T)
  const int j = row % T_;
  const int kvq = row / T_;
  const int kvh = kvq % KV_, b = kvq / KV_;
  bf16x8 vv;
  if (j < P_) {
    const float* src = pk + ((long)((b * P_ + j) * KV_ + kvh)) * HD_ + ch;
    vv = cvt8(*(const float4*)src, *(const float4*)(src + 4));
  } else {
    vv = *(const bf16x8*)(kn + ((long)((b * S_ + (j - P_)) * KV_ + kvh)) * HD_ + ch);
  }
  *(bf16x8*)(kc + (long)row * HD_ + ch) = vv;
}

// ---------------- GEMM: C[M,N] = A[M,K] @ Bt[N,K]^T, bf16 in, fp32 acc ------
// 128x128 tile, BK=32, register-prefetch double buffer (round-2 proven best).
template <typename OutT>
__global__ __launch_bounds__(256, 2) void gemm_bt(const __bf16* __restrict__ A,
                                                  const __bf16* __restrict__ Bt,
                                                  OutT* __restrict__ C,
                                                  int M, int N, int K) {
  __shared__ __align__(16) __bf16 As[128][40];
  __shared__ __align__(16) __bf16 Bs[128][40];
  const int t = threadIdx.x;
  const int lane = t & 63, wave = t >> 6;
  const int wm = (wave >> 1) * 64, wn = (wave & 1) * 64;
  const int l15 = lane & 15, quad = lane >> 4;
  const long m0 = (long)blockIdx.y * 128, n0 = (long)blockIdx.x * 128;

  const int srow = t >> 2;
  const int sc8 = (t & 3) * 8;
  const __bf16* Ap = A + (m0 + srow) * K + sc8;
  const __bf16* Bp = Bt + (n0 + srow) * K + sc8;
  const long rstep = (long)64 * K;

  f32x4 acc[4][4];
#pragma unroll
  for (int i = 0; i < 4; ++i)
#pragma unroll
    for (int j = 0; j < 4; ++j)
#pragma unroll
      for (int e = 0; e < 4; ++e) acc[i][j][e] = 0.0f;

  bf16x8 ra0 = *(const bf16x8*)(Ap);
  bf16x8 ra1 = *(const bf16x8*)(Ap + rstep);
  bf16x8 rb0 = *(const bf16x8*)(Bp);
  bf16x8 rb1 = *(const bf16x8*)(Bp + rstep);

  const int nk = K >> 5;
  for (int kt = 0; kt < nk; ++kt) {
    __syncthreads();
    *(bf16x8*)(&As[srow][sc8]) = ra0;
    *(bf16x8*)(&As[64 + srow][sc8]) = ra1;
    *(bf16x8*)(&Bs[srow][sc8]) = rb0;
    *(bf16x8*)(&Bs[64 + srow][sc8]) = rb1;
    if (kt + 1 < nk) {
      const __bf16* An = Ap + (kt + 1) * 32;
      const __bf16* Bn = Bp + (kt + 1) * 32;
      ra0 = *(const bf16x8*)(An);
      ra1 = *(const bf16x8*)(An + rstep);
      rb0 = *(const bf16x8*)(Bn);
      rb1 = *(const bf16x8*)(Bn + rstep);
    }
    __syncthreads();
    bf16x8 aF[4], bF[4];
#pragma unroll
    for (int i = 0; i < 4; ++i)
      aF[i] = *(const bf16x8*)(&As[wm + i * 16 + l15][quad * 8]);
#pragma unroll
    for (int i = 0; i < 4; ++i)
      bF[i] = *(const bf16x8*)(&Bs[wn + i * 16 + l15][quad * 8]);
#pragma unroll
    for (int i = 0; i < 4; ++i)
#pragma unroll
      for (int j = 0; j < 4; ++j)
        acc[i][j] = __builtin_amdgcn_mfma_f32_16x16x32_bf16(aF[i], bF[j],
                                                            acc[i][j], 0, 0, 0);
  }

#pragma unroll
  for (int i = 0; i < 4; ++i) {
    const long r0 = m0 + wm + i * 16 + quad * 4;
#pragma unroll
    for (int j = 0; j < 4; ++j) {
      const long col = n0 + wn + j * 16 + l15;
#pragma unroll
      for (int r = 0; r < 4; ++r)
        C[(r0 + r) * N + col] = (OutT)acc[i][j][r];
    }
  }
}

// ---------------- fused causal GQA flash attention ---------------------------
// grid (8, H, B), 512 threads (8 waves). Block = 256 q-rows of one head; wave
// owns 32 rows. 64-key tiles. S^T = K·Q^T trick: softmax reductions are
// 2-deep shfls; P stored to LDS A-layout via b64 writes; no cross-wave P.
__global__ __launch_bounds__(512, 4) void attn_kernel(
    __bf16* qio,                     // [B,S,H,HD] in: Q, out: attn out (in-place)
    const __bf16* __restrict__ kc,   // [B,KV,T,HD]
    const __bf16* __restrict__ vt) { // [B,KV,HD,T]
  __shared__ __align__(16) __bf16 Ks[64][136];   // [key][hd]    17408 B
  __shared__ __align__(16) __bf16 Vs[128][72];   // [hd][key]    18432 B
  __shared__ __align__(16) __bf16 Ps[256][72];   // [q][key]     36864 B
  const int t = threadIdx.x;
  const int lane = t & 63, w = t >> 6;           // wave 0..7
  const int l15 = lane & 15, quad = lane >> 4;
  const int s0 = (7 - (int)blockIdx.x) * 256;    // heavy blocks dispatch first
  const int h = blockIdx.y, b = blockIdx.z;
  const int kvh = h >> 2;  // G=4
  const long kcb = (long)(b * KV_ + kvh) * T_;   // key-row base in kc
  const long vtb = (long)(b * KV_ + kvh) * HD_;  // hd-row base in vt

  // Q fragments (identical layout serves as MFMA B-operand): row q, cols hd
  bf16x8 aQ[2][4];
#pragma unroll
  for (int mi = 0; mi < 2; ++mi) {
    const int qrow = s0 + w * 32 + mi * 16 + l15;
    const __bf16* qp = qio + ((long)((b * S_ + qrow) * H_ + h)) * HD_ + quad * 8;
#pragma unroll
    for (int kt = 0; kt < 4; ++kt) aQ[mi][kt] = *(const bf16x8*)(qp + kt * 32);
  }

  f32x4 O[2][8];
#pragma unroll
  for (int mi = 0; mi < 2; ++mi)
#pragma unroll
    for (int f = 0; f < 8; ++f)
#pragma unroll
      for (int e = 0; e < 4; ++e) O[mi][f][e] = 0.0f;
  float m_r[2] = {-__builtin_inff(), -__builtin_inff()};
  float l_r[2] = {0.0f, 0.0f};

  const float C2 = 1.4426950408889634f * 0.08838834764831845f;  // log2e/sqrt(128)
  const int ntiles = (P_ + s0 + 256) / 64;
  const int wave_last_key = P_ + s0 + w * 32 + 31;
  const int wave_min_bound = P_ + s0 + w * 32;

  for (int tile = 0; tile < ntiles; ++tile) {
    const int j0 = tile * 64;
    __syncthreads();
    // stage K tile [64 keys][128 hd] from bf16 concat cache (uniform path)
#pragma unroll
    for (int p = 0; p < 2; ++p) {
      const int li = p * 512 + t;
      const int key = li >> 4, ch = (li & 15) * 8;
      *(bf16x8*)(&Ks[key][ch]) =
          *(const bf16x8*)(kc + (kcb + j0 + key) * HD_ + ch);
    }
    // stage V^T tile [128 hd][64 keys]
#pragma unroll
    for (int p = 0; p < 2; ++p) {
      const int li = p * 512 + t;
      const int hd = li >> 3, k8 = (li & 7) * 8;
      *(bf16x8*)(&Vs[hd][k8]) =
          *(const bf16x8*)(vt + (vtb + hd) * T_ + j0 + k8);
    }
    __syncthreads();

    if (j0 > wave_last_key) continue;  // wave-uniform; barriers stay aligned

    const bool need_mask = (j0 + 63 > wave_min_bound);
    float alpha_l[2];

#pragma unroll
    for (int mi = 0; mi < 2; ++mi) {
      // S^T = K·Q^T : C col = q (lane&15), row = key (quad*4+reg)
      f32x4 sc[4];
#pragma unroll
      for (int kf = 0; kf < 4; ++kf)
#pragma unroll
        for (int e = 0; e < 4; ++e) sc[kf][e] = 0.0f;
#pragma unroll
      for (int kf = 0; kf < 4; ++kf)
#pragma unroll
        for (int kt = 0; kt < 4; ++kt) {
          bf16x8 bk = *(const bf16x8*)(&Ks[kf * 16 + l15][kt * 32 + quad * 8]);
          sc[kf] = __builtin_amdgcn_mfma_f32_16x16x32_bf16(bk, aQ[mi][kt],
                                                           sc[kf], 0, 0, 0);
        }
      const int boundq = P_ + s0 + w * 32 + mi * 16 + l15;  // this lane's q
      float v[4][4];
      float mloc = -__builtin_inff();
#pragma unroll
      for (int kf = 0; kf < 4; ++kf) {
        const int kb = j0 + kf * 16 + quad * 4;
#pragma unroll
        for (int r = 0; r < 4; ++r) {
          float x = sc[kf][r];
          if (need_mask && (kb + r > boundq)) x = -__builtin_inff();
          v[kf][r] = x;
          mloc = fmaxf(mloc, x);
        }
      }
      // row-max: local regs + 2-deep quad shuffle
      float mt = fmaxf(mloc, __shfl_xor(mloc, 16));
      mt = fmaxf(mt, __shfl_xor(mt, 32));
      const float mn = fmaxf(m_r[mi], mt);
      const float al = exp2f((m_r[mi] - mn) * C2);
      m_r[mi] = mn;
      float sloc = 0.0f;
      const int prow = w * 32 + mi * 16 + l15;
#pragma unroll
      for (int kf = 0; kf < 4; ++kf) {
        const float p0 = exp2f((v[kf][0] - mn) * C2);
        const float p1 = exp2f((v[kf][1] - mn) * C2);
        const float p2 = exp2f((v[kf][2] - mn) * C2);
        const float p3 = exp2f((v[kf][3] - mn) * C2);
        sloc += (p0 + p1) + (p2 + p3);
        bf16x4 pq;
        pq[0] = (__bf16)p0; pq[1] = (__bf16)p1;
        pq[2] = (__bf16)p2; pq[3] = (__bf16)p3;
        *(bf16x4*)(&Ps[prow][kf * 16 + quad * 4]) = pq;  // one b64 write
      }
      float rs = sloc + __shfl_xor(sloc, 16);
      rs += __shfl_xor(rs, 32);
      l_r[mi] = l_r[mi] * al + rs;
      alpha_l[mi] = al;
    }

    // rescale O (alpha redistributed from q=lane&15 domain to q=quad*4+r)
#pragma unroll
    for (int mi = 0; mi < 2; ++mi)
#pragma unroll
      for (int r = 0; r < 4; ++r) {
        const float aO = __shfl(alpha_l[mi], quad * 4 + r);
#pragma unroll
        for (int f = 0; f < 8; ++f) O[mi][f][r] *= aO;
      }

    // P writes -> P reads: same-wave, disjoint rows; fence the DS queue
    __asm__ volatile("s_waitcnt lgkmcnt(0)" ::: "memory");

    // PV: O[32 q][128 hd] += P[32][64] @ V[64][128]
#pragma unroll
    for (int kf2 = 0; kf2 < 2; ++kf2) {
      bf16x8 aP0 = *(const bf16x8*)(&Ps[w * 32 + l15][kf2 * 32 + quad * 8]);
      bf16x8 aP1 = *(const bf16x8*)(&Ps[w * 32 + 16 + l15][kf2 * 32 + quad * 8]);
#pragma unroll
      for (int f = 0; f < 8; ++f) {
        bf16x8 bV = *(const bf16x8*)(&Vs[f * 16 + l15][kf2 * 32 + quad * 8]);
        O[0][f] = __builtin_amdgcn_mfma_f32_16x16x32_bf16(aP0, bV, O[0][f], 0, 0, 0);
        O[1][f] = __builtin_amdgcn_mfma_f32_16x16x32_bf16(aP1, bV, O[1][f], 0, 0, 0);
      }
    }
  }

  // epilogue: normalize (1/l redistributed like alpha), store in-place
#pragma unroll
  for (int mi = 0; mi < 2; ++mi) {
    const float inv = 1.0f / l_r[mi];
#pragma unroll
    for (int r = 0; r < 4; ++r) {
      const float invr = __shfl(inv, quad * 4 + r);
      const long row =
          (long)((b * S_ + s0 + w * 32 + mi * 16 + quad * 4 + r) * H_ + h);
#pragma unroll
      for (int f = 0; f < 8; ++f)
        qio[row * HD_ + f * 16 + l15] = (__bf16)(O[mi][f][r] * invr);
    }
  }
}

extern "C" void kernel_launch(void* const* d_in, const int* in_sizes, int n_in,
                              void* d_out, int out_size, void* d_ws, size_t ws_size,
                              hipStream_t stream) {
  const float* x  = (const float*)d_in[0];
  const float* pk = (const float*)d_in[1];
  const float* pv = (const float*)d_in[2];
  const float* Wq = (const float*)d_in[3];
  const float* Wk = (const float*)d_in[4];
  const float* Wv = (const float*)d_in[5];
  const float* Wo = (const float*)d_in[6];
  float* out = (float*)d_out;
  char* ws = (char*)d_ws;
  __bf16* wt = (__bf16*)(ws);                       // 33,554,432 B  W^T bf16
  __bf16* kc = (__bf16*)(ws);                       // 12,582,912 B  (aliases wt, used after last wt use)
  __bf16* q  = (__bf16*)(ws + (size_t)33554432);    // 33,554,432 B  [B,S,H,HD]
  __bf16* kn = (__bf16*)(ws + (size_t)67108864);    //  8,388,608 B  [B,S,KV,HD]
  __bf16* vn = (__bf16*)(ws + (size_t)75497472);    //  8,388,608 B  [B,S,KV,HD]
  __bf16* xb = (__bf16*)(ws + (size_t)83886080);    // 33,554,432 B  x bf16
  __bf16* vt = (__bf16*)(ws + (size_t)83886080);    // 12,582,912 B  (aliases dead xb)

  dim3 tb(32, 8);
  cvt_f32_bf16<<<8192, 256, 0, stream>>>(x, xb);
  // q = x @ Wq
  transpose2d<<<dim3(128, 128), tb, 0, stream>>>(Wq, wt, D_, D_);
  gemm_bt<__bf16><<<dim3(32, 32), 256, 0, stream>>>(xb, wt, q, B_ * S_, D_, D_);
  // k_new = x @ Wk
  transpose2d<<<dim3(32, 128), tb, 0, stream>>>(Wk, wt, D_, KV_ * HD_);
  gemm_bt<__bf16><<<dim3(8, 32), 256, 0, stream>>>(xb, wt, kn, B_ * S_, KV_ * HD_, D_);
  // v_new = x @ Wv  (last use of xb and of wt-as-weights until Wo)
  transpose2d<<<dim3(32, 128), tb, 0, stream>>>(Wv, wt, D_, KV_ * HD_);
  gemm_bt<__bf16><<<dim3(8, 32), 256, 0, stream>>>(xb, wt, vn, B_ * S_, KV_ * HD_, D_);
  // concat caches: V^T (into dead xb), K bf16 (into dead wt)
  build_vt<<<dim3(96, 4, 16), tb, 0, stream>>>(pv, vn, vt);
  build_kc<<<3072, 256, 0, stream>>>(pk, kn, kc);
  // attention (in-place on q)
  attn_kernel<<<dim3(8, 32, 2), 512, 0, stream>>>(q, kc, vt);
  // out = attn @ Wo  (f32 output; overwrites kc region with Wo^T)
  transpose2d<<<dim3(128, 128), tb, 0, stream>>>(Wo, wt, D_, D_);
  gemm_bt<float><<<dim3(32, 32), 256, 0, stream>>>(q, wt, out, B_ * S_, D_, D_);
}